// Round 1
// baseline (207.053 us; speedup 1.0000x reference)
//
#include <hip/hip_runtime.h>
#include <stdint.h>
#include <stddef.h>

#define SEQ   2048
#define HD    64
#define DM    1024
#define NHEAD 16

typedef __bf16 bf16x8 __attribute__((ext_vector_type(8)));
typedef float  f32x4  __attribute__((ext_vector_type(4)));

#define MFMA16x16(a, b, c) __builtin_amdgcn_mfma_f32_16x16x32_bf16((a), (b), (c), 0, 0, 0)

__device__ __forceinline__ void gload16(const void* g, void* lds_uniform) {
    __builtin_amdgcn_global_load_lds(
        (const __attribute__((address_space(1))) uint32_t*)g,
        (__attribute__((address_space(3))) uint32_t*)lds_uniform, 16, 0, 0);
}

// ---------------- fp32 -> bf16 convert ----------------
__global__ void cvt_kernel(const float* __restrict__ in, __bf16* __restrict__ out, int n) {
    int i = (blockIdx.x * blockDim.x + threadIdx.x) * 4;
    if (i >= n) return;
    const float4 v = *(const float4*)(in + i);
    __bf16 o[4] = {(__bf16)v.x, (__bf16)v.y, (__bf16)v.z, (__bf16)v.w};
    *(uint64_t*)(out + i) = *(const uint64_t*)o;
}

// ---------------- rope tables: cos/sin[pos*32 + p] ----------------
__global__ void rope_tab_kernel(float* __restrict__ ct, float* __restrict__ st) {
    int i = blockIdx.x * blockDim.x + threadIdx.x;   // pos*32 + p, 65536 total
    int p = i & 31;
    int pos = i >> 5;
    float freq = expf(-(float)p * (logf(10000.0f) / 32.0f));  // theta^(-p/32)
    float ang = (float)pos * freq;
    ct[i] = cosf(ang);
    st[i] = sinf(ang);
}

// ---------------- rope apply in place on Q (with 0.125 scale) and K ----------------
__global__ void rope_apply_kernel(__bf16* __restrict__ Qb, __bf16* __restrict__ Kb,
                                  const int* __restrict__ pos,
                                  const float* __restrict__ ct, const float* __restrict__ st) {
    int tid = blockIdx.x * blockDim.x + threadIdx.x;
    const int per = 32 * SEQ * 8;     // 8-elem chunks per tensor
    int isK = tid >= per;
    int t = isK ? tid - per : tid;
    int c8 = t & 7;                   // which 8-elem chunk of the 64 dims
    int l  = (t >> 3) & (SEQ - 1);
    int bh = t >> 14;
    __bf16* base = (isK ? Kb : Qb) + ((size_t)(bh * SEQ + l) * HD) + c8 * 8;
    int pb = pos[l] * 32 + c8 * 4;
    float scale = isK ? 1.0f : 0.125f;   // fold 1/sqrt(64) into Q (exact in bf16)
    bf16x8 v = *(const bf16x8*)base;
    bf16x8 o;
    #pragma unroll
    for (int j = 0; j < 4; ++j) {
        float cs = ct[pb + j], sn = st[pb + j];
        float e = (float)v[2 * j], d = (float)v[2 * j + 1];
        o[2 * j]     = (__bf16)(scale * (cs * e - sn * d));
        o[2 * j + 1] = (__bf16)(scale * (sn * e + cs * d));
    }
    *(bf16x8*)base = o;
}

// ---------------- GEMM: C[m][n] = sum_k A[m][k] * W[n][k]  (both K-contiguous) --------
// 128x128 tile, BK=64, 4 waves (2x2 of 64x64), global_load_lds(16B) staging with
// pre-swizzled source; LDS rows 128B, chunk XOR (row&7) swizzle -> conflict-free b128.
// MODE 0: N=3072 QKV; epilogue scatters bf16 to Q[B,H,L,64], K[B,H,L,64], VT[B,H,64,L]
//         via a per-wave LDS transpose tile so all global stores are 16B.
// MODE 1: plain fp32 C output.
template <int MODE>
__global__ __launch_bounds__(256, 2)
void gemm_bt_kernel(const __bf16* __restrict__ A, const __bf16* __restrict__ W,
                    float* __restrict__ C, __bf16* __restrict__ Qb,
                    __bf16* __restrict__ Kb, __bf16* __restrict__ VTb,
                    int N, int K) {
    __shared__ __align__(16) char smem[32768];
    char* As = smem;
    char* Bs = smem + 16384;
    const int lane = threadIdx.x & 63;
    const int w    = threadIdx.x >> 6;
    const int bn = blockIdx.x, bm = blockIdx.y;
    const int rbase = (w >> 1) * 64;
    const int cbase = (w & 1) * 64;

    f32x4 acc[4][4] = {};

    const int kt_iters = K >> 6;
    for (int kt = 0; kt < kt_iters; ++kt) {
        #pragma unroll
        for (int c = 0; c < 4; ++c) {
            int id = (c * 4 + w) * 64 + lane;
            int row = id >> 3, cc = id & 7;
            int koff = kt * 64 + ((cc ^ (row & 7)) << 3);
            gload16(A + (size_t)(bm * 128 + row) * K + koff, As + (c * 4 + w) * 1024);
            gload16(W + (size_t)(bn * 128 + row) * K + koff, Bs + (c * 4 + w) * 1024);
        }
        __syncthreads();
        #pragma unroll
        for (int ks = 0; ks < 2; ++ks) {
            bf16x8 af[4], bfr[4];
            #pragma unroll
            for (int i = 0; i < 4; ++i) {
                int row = rbase + i * 16 + (lane & 15);
                int c = ks * 4 + (lane >> 4);
                af[i] = *(const bf16x8*)(As + row * 128 + ((c ^ (row & 7)) << 4));
            }
            #pragma unroll
            for (int j = 0; j < 4; ++j) {
                int row = cbase + j * 16 + (lane & 15);
                int c = ks * 4 + (lane >> 4);
                bfr[j] = *(const bf16x8*)(Bs + row * 128 + ((c ^ (row & 7)) << 4));
            }
            #pragma unroll
            for (int i = 0; i < 4; ++i)
                #pragma unroll
                for (int j = 0; j < 4; ++j)
                    acc[i][j] = MFMA16x16(af[i], bfr[j], acc[i][j]);
        }
        __syncthreads();
    }

    if (MODE == 1) {
        #pragma unroll
        for (int i = 0; i < 4; ++i)
            #pragma unroll
            for (int j = 0; j < 4; ++j)
                #pragma unroll
                for (int r = 0; r < 4; ++r) {
                    int m = bm * 128 + rbase + i * 16 + (lane >> 4) * 4 + r;
                    int n = bn * 128 + cbase + j * 16 + (lane & 15);
                    C[(size_t)m * N + n] = acc[i][j][r];
                }
    } else {
        const int which = bn >> 3;    // 0=Q 1=K 2=V (128-col block never crosses)
        char* T = smem + w * 8192;    // per-wave 64x64 bf16, swizzled
        #pragma unroll
        for (int i = 0; i < 4; ++i)
            #pragma unroll
            for (int j = 0; j < 4; ++j)
                #pragma unroll
                for (int r = 0; r < 4; ++r) {
                    int mi = i * 16 + (lane >> 4) * 4 + r;
                    int ni = j * 16 + (lane & 15);
                    __bf16 v = (__bf16)acc[i][j][r];
                    if (which == 2)
                        *(__bf16*)(T + ni * 128 + ((mi * 2) ^ ((ni & 7) << 4))) = v;
                    else
                        *(__bf16*)(T + mi * 128 + ((ni * 2) ^ ((mi & 7) << 4))) = v;
                }
        #pragma unroll
        for (int it = 0; it < 8; ++it) {
            int id = it * 64 + lane;
            int row = id >> 3, cc = id & 7;
            bf16x8 v = *(const bf16x8*)(T + row * 128 + ((cc ^ (row & 7)) << 4));
            if (which == 2) {
                int n = bn * 128 + cbase + row;       // d-major row
                int m = bm * 128 + rbase + cc * 8;    // 8 consecutive l
                int b = m >> 11, l = m & (SEQ - 1);
                int h = (n & (DM - 1)) >> 6, d = n & 63;
                *(bf16x8*)(VTb + ((size_t)((b * NHEAD + h) * HD + d) * SEQ) + l) = v;
            } else {
                int m = bm * 128 + rbase + row;
                int n = bn * 128 + cbase + cc * 8;    // 8 consecutive d
                int b = m >> 11, l = m & (SEQ - 1);
                int h = (n & (DM - 1)) >> 6, d = n & 63;
                __bf16* dst = which ? Kb : Qb;
                *(bf16x8*)(dst + ((size_t)(b * NHEAD + h) * SEQ + l) * HD + d) = v;
            }
        }
    }
}

// ---------------- causal flash attention ----------------
// grid (L/64, B*H); 4 waves; wave owns 16 q-rows; KV block = 64.
// Q frags in regs; K,VT staged to swizzled LDS via global_load_lds; P via per-wave
// swizzled LDS tile. S and O share the row->lane map so rescale is broadcast-free.
__global__ __launch_bounds__(256, 2)
void attn_kernel(const __bf16* __restrict__ Q, const __bf16* __restrict__ K,
                 const __bf16* __restrict__ VT, __bf16* __restrict__ O) {
    __shared__ __align__(16) char smem[24576];
    char* Ks = smem;            // [64][64] bf16 swz
    char* Vs = smem + 8192;     // VT tile [64 d][64 j] bf16 swz
    const int lane = threadIdx.x & 63;
    const int w    = threadIdx.x >> 6;
    char* Ps = smem + 16384 + w * 2048;   // per-wave [16 q][64 j] bf16 swz
    const int qb = blockIdx.x, bh = blockIdx.y;

    const __bf16* Qbh  = Q  + (size_t)bh * SEQ * HD;
    const __bf16* Kbh  = K  + (size_t)bh * SEQ * HD;
    const __bf16* VTbh = VT + (size_t)bh * HD * SEQ;

    const int qrow = qb * 64 + w * 16 + (lane & 15);
    bf16x8 qf[2];
    qf[0] = *(const bf16x8*)(Qbh + (size_t)qrow * HD + (lane >> 4) * 8);
    qf[1] = *(const bf16x8*)(Qbh + (size_t)qrow * HD + 32 + (lane >> 4) * 8);

    f32x4 o[4] = {};
    float mrow[4] = {-1e30f, -1e30f, -1e30f, -1e30f};
    float lrow[4] = {0.f, 0.f, 0.f, 0.f};

    for (int kb = 0; kb <= qb; ++kb) {
        #pragma unroll
        for (int c = 0; c < 2; ++c) {
            int id = (c * 4 + w) * 64 + lane;
            int row = id >> 3, cc = id & 7;
            int sw = (cc ^ (row & 7)) << 3;
            gload16(Kbh + (size_t)(kb * 64 + row) * HD + sw, Ks + (c * 4 + w) * 1024);
            gload16(VTbh + (size_t)row * SEQ + kb * 64 + sw, Vs + (c * 4 + w) * 1024);
        }
        __syncthreads();

        f32x4 s[4];
        #pragma unroll
        for (int jt = 0; jt < 4; ++jt) {
            f32x4 z = {};
            #pragma unroll
            for (int ks = 0; ks < 2; ++ks) {
                int row = jt * 16 + (lane & 15);
                int c = ks * 4 + (lane >> 4);
                bf16x8 kf = *(const bf16x8*)(Ks + row * 128 + ((c ^ (row & 7)) << 4));
                z = MFMA16x16(qf[ks], kf, z);
            }
            s[jt] = z;
        }

        if (kb == qb) {
            #pragma unroll
            for (int jt = 0; jt < 4; ++jt) {
                int j = kb * 64 + jt * 16 + (lane & 15);
                #pragma unroll
                for (int r = 0; r < 4; ++r) {
                    int i = qb * 64 + w * 16 + (lane >> 4) * 4 + r;
                    if (j > i) s[jt][r] = -1e30f;
                }
            }
        }

        float alpha[4];
        #pragma unroll
        for (int r = 0; r < 4; ++r) {
            float mx = fmaxf(fmaxf(s[0][r], s[1][r]), fmaxf(s[2][r], s[3][r]));
            mx = fmaxf(mx, __shfl_xor(mx, 1));
            mx = fmaxf(mx, __shfl_xor(mx, 2));
            mx = fmaxf(mx, __shfl_xor(mx, 4));
            mx = fmaxf(mx, __shfl_xor(mx, 8));
            float mn = fmaxf(mrow[r], mx);
            alpha[r] = __expf(mrow[r] - mn);
            mrow[r] = mn;
            float rs = 0.f;
            #pragma unroll
            for (int jt = 0; jt < 4; ++jt) {
                float p = __expf(s[jt][r] - mn);
                s[jt][r] = p;
                rs += p;
            }
            rs += __shfl_xor(rs, 1);
            rs += __shfl_xor(rs, 2);
            rs += __shfl_xor(rs, 4);
            rs += __shfl_xor(rs, 8);
            lrow[r] = lrow[r] * alpha[r] + rs;
        }

        // P -> per-wave LDS (bf16, swizzled)
        #pragma unroll
        for (int jt = 0; jt < 4; ++jt)
            #pragma unroll
            for (int r = 0; r < 4; ++r) {
                int qr = (lane >> 4) * 4 + r;
                int jj = (jt * 16 + (lane & 15)) * 2;
                *(__bf16*)(Ps + qr * 128 + (jj ^ ((qr & 7) << 4))) = (__bf16)s[jt][r];
            }

        #pragma unroll
        for (int dt = 0; dt < 4; ++dt)
            #pragma unroll
            for (int r = 0; r < 4; ++r)
                o[dt][r] *= alpha[r];

        #pragma unroll
        for (int js = 0; js < 2; ++js) {
            int prow = lane & 15;
            int cb = js * 4 + (lane >> 4);
            bf16x8 pf = *(const bf16x8*)(Ps + prow * 128 + ((cb ^ (prow & 7)) << 4));
            #pragma unroll
            for (int dt = 0; dt < 4; ++dt) {
                int vrow = dt * 16 + (lane & 15);
                bf16x8 vf = *(const bf16x8*)(Vs + vrow * 128 + ((cb ^ (vrow & 7)) << 4));
                o[dt] = MFMA16x16(pf, vf, o[dt]);
            }
        }
        __syncthreads();
    }

    float inv[4];
    #pragma unroll
    for (int r = 0; r < 4; ++r) inv[r] = 1.0f / lrow[r];

    // stage O tile [64 q][64 d] into smem (reuse Ks region), then coalesced store
    char* Os = smem;
    #pragma unroll
    for (int dt = 0; dt < 4; ++dt)
        #pragma unroll
        for (int r = 0; r < 4; ++r) {
            int orow = w * 16 + (lane >> 4) * 4 + r;
            int oc = (dt * 16 + (lane & 15)) * 2;
            *(__bf16*)(Os + orow * 128 + (oc ^ ((orow & 7) << 4))) = (__bf16)(o[dt][r] * inv[r]);
        }
    __syncthreads();

    const int b = bh >> 4, h = bh & 15;
    #pragma unroll
    for (int c = 0; c < 2; ++c) {
        int id = c * 256 + threadIdx.x;
        int row = id >> 3, cc = id & 7;
        bf16x8 v = *(const bf16x8*)(Os + row * 128 + ((cc ^ (row & 7)) << 4));
        *(bf16x8*)(O + (size_t)(b * SEQ + qb * 64 + row) * DM + h * HD + cc * 8) = v;
    }
}

extern "C" void kernel_launch(void* const* d_in, const int* in_sizes, int n_in,
                              void* d_out, int out_size, void* d_ws, size_t ws_size,
                              hipStream_t stream) {
    const float* x  = (const float*)d_in[0];
    const float* wq = (const float*)d_in[1];
    const float* wk = (const float*)d_in[2];
    const float* wv = (const float*)d_in[3];
    const float* wo = (const float*)d_in[4];
    const int* tpos = (const int*)d_in[5];
    float* out = (float*)d_out;
    char* ws = (char*)d_ws;

    __bf16* xb   = (__bf16*)(ws);                        // 8 MB  [4096][1024]
    __bf16* wqkv = (__bf16*)(ws + (size_t)(8  << 20));   // 6 MB  [3072][1024]
    __bf16* wob  = (__bf16*)(ws + (size_t)(14 << 20));   // 2 MB  [1024][1024]
    __bf16* Qb   = (__bf16*)(ws + (size_t)(16 << 20));   // 8 MB  [32][2048][64]
    __bf16* Kb   = (__bf16*)(ws + (size_t)(24 << 20));   // 8 MB  [32][2048][64]
    __bf16* VTb  = (__bf16*)(ws + (size_t)(32 << 20));   // 8 MB  [32][64][2048]
    __bf16* Ob   = (__bf16*)(ws + (size_t)(40 << 20));   // 8 MB  [4096][1024]
    float* ct    = (float*)(ws + (size_t)(48 << 20));            // 256 KB
    float* st    = (float*)(ws + (size_t)(48 << 20) + 262144);   // 256 KB

    cvt_kernel<<<4096, 256, 0, stream>>>(x, xb, 4194304);
    cvt_kernel<<<1024, 256, 0, stream>>>(wq, wqkv, 1048576);
    cvt_kernel<<<1024, 256, 0, stream>>>(wk, wqkv + 1048576, 1048576);
    cvt_kernel<<<1024, 256, 0, stream>>>(wv, wqkv + 2097152, 1048576);
    cvt_kernel<<<1024, 256, 0, stream>>>(wo, wob, 1048576);
    rope_tab_kernel<<<256, 256, 0, stream>>>(ct, st);
    gemm_bt_kernel<0><<<dim3(24, 32), 256, 0, stream>>>(xb, wqkv, nullptr, Qb, Kb, VTb, 3072, 1024);
    rope_apply_kernel<<<4096, 256, 0, stream>>>(Qb, Kb, tpos, ct, st);
    attn_kernel<<<dim3(32, 32), 256, 0, stream>>>(Qb, Kb, VTb, Ob);
    gemm_bt_kernel<1><<<dim3(8, 32), 256, 0, stream>>>(Ob, wob, out, nullptr, nullptr, nullptr, 1024, 1024);
}

// Round 3
// 142.118 us; speedup vs baseline: 1.4569x; 1.4569x over previous
//
#include <hip/hip_runtime.h>
#include <stdint.h>
#include <stddef.h>

#define SEQ   2048
#define HD    64
#define DM    1024
#define NHEAD 16

typedef __bf16 bf16x8 __attribute__((ext_vector_type(8)));
typedef float  f32x4  __attribute__((ext_vector_type(4)));

#define MFMA16x16(a, b, c) __builtin_amdgcn_mfma_f32_16x16x32_bf16((a), (b), (c), 0, 0, 0)

__device__ __forceinline__ void gload16(const void* g, void* lds_uniform) {
    __builtin_amdgcn_global_load_lds(
        (const __attribute__((address_space(1))) uint32_t*)g,
        (__attribute__((address_space(3))) uint32_t*)lds_uniform, 16, 0, 0);
}

// ---------------- fp32 -> bf16 convert (x) ----------------
__global__ void cvt_kernel(const float* __restrict__ in, __bf16* __restrict__ out, int n) {
    int i = (blockIdx.x * blockDim.x + threadIdx.x) * 4;
    if (i >= n) return;
    const float4 v = *(const float4*)(in + i);
    __bf16 o[4] = {(__bf16)v.x, (__bf16)v.y, (__bf16)v.z, (__bf16)v.w};
    *(uint64_t*)(out + i) = *(const uint64_t*)o;
}

// ---------------- fp32 -> bf16 convert, all 4 weight mats in one launch -------------
__global__ void cvt4_kernel(const float* __restrict__ wq, const float* __restrict__ wk,
                            const float* __restrict__ wv, const float* __restrict__ wo,
                            __bf16* __restrict__ wqkv, __bf16* __restrict__ wob) {
    int g = blockIdx.x >> 10;                                 // 0..3
    int i = ((blockIdx.x & 1023) * 256 + threadIdx.x) * 4;    // 0..1048575
    const float* src = (g == 0) ? wq : (g == 1) ? wk : (g == 2) ? wv : wo;
    __bf16* dst = (g == 3) ? wob : (wqkv + (size_t)g * 1048576);
    const float4 v = *(const float4*)(src + i);
    __bf16 o[4] = {(__bf16)v.x, (__bf16)v.y, (__bf16)v.z, (__bf16)v.w};
    *(uint64_t*)(dst + i) = *(const uint64_t*)o;
}

// ---------------- rope tables: cos/sin[pos*32 + p] ----------------
__global__ void rope_tab_kernel(float* __restrict__ ct, float* __restrict__ st) {
    int i = blockIdx.x * blockDim.x + threadIdx.x;   // pos*32 + p, 65536 total
    int p = i & 31;
    int pos = i >> 5;
    float freq = expf(-(float)p * (logf(10000.0f) / 32.0f));  // theta^(-p/32)
    float ang = (float)pos * freq;
    ct[i] = cosf(ang);
    st[i] = sinf(ang);
}

// ---------------- GEMM: C[m][n] = sum_k A[m][k] * W[n][k]  (both K-contiguous) --------
// 128x128 tile, BK=64, 4 waves (2x2 of 64x64), global_load_lds(16B) staging with
// pre-swizzled source; LDS rows 128B, chunk XOR (row&7) swizzle -> conflict-free b128.
// MODE 0: N=3072 QKV; epilogue scatters bf16 to Q[B,H,L,64], K[B,H,L,64], VT[B,H,64,L]
//         via a per-wave LDS transpose tile; RoPE (and 1/8 Q-scale) fused for Q,K.
// MODE 1: plain fp32 C output.
template <int MODE>
__global__ __launch_bounds__(256, 2)
void gemm_bt_kernel(const __bf16* __restrict__ A, const __bf16* __restrict__ W,
                    float* __restrict__ C, __bf16* __restrict__ Qb,
                    __bf16* __restrict__ Kb, __bf16* __restrict__ VTb,
                    const int* __restrict__ tpos, const float* __restrict__ ct,
                    const float* __restrict__ st, int N, int K) {
    __shared__ __align__(16) char smem[32768];
    char* As = smem;
    char* Bs = smem + 16384;
    const int lane = threadIdx.x & 63;
    const int w    = threadIdx.x >> 6;
    const int bn = blockIdx.x, bm = blockIdx.y;
    const int rbase = (w >> 1) * 64;
    const int cbase = (w & 1) * 64;

    f32x4 acc[4][4] = {};

    const int kt_iters = K >> 6;
    for (int kt = 0; kt < kt_iters; ++kt) {
        #pragma unroll
        for (int c = 0; c < 4; ++c) {
            int id = (c * 4 + w) * 64 + lane;
            int row = id >> 3, cc = id & 7;
            int koff = kt * 64 + ((cc ^ (row & 7)) << 3);
            gload16(A + (size_t)(bm * 128 + row) * K + koff, As + (c * 4 + w) * 1024);
            gload16(W + (size_t)(bn * 128 + row) * K + koff, Bs + (c * 4 + w) * 1024);
        }
        __syncthreads();
        #pragma unroll
        for (int ks = 0; ks < 2; ++ks) {
            bf16x8 af[4], bfr[4];
            #pragma unroll
            for (int i = 0; i < 4; ++i) {
                int row = rbase + i * 16 + (lane & 15);
                int c = ks * 4 + (lane >> 4);
                af[i] = *(const bf16x8*)(As + row * 128 + ((c ^ (row & 7)) << 4));
            }
            #pragma unroll
            for (int j = 0; j < 4; ++j) {
                int row = cbase + j * 16 + (lane & 15);
                int c = ks * 4 + (lane >> 4);
                bfr[j] = *(const bf16x8*)(Bs + row * 128 + ((c ^ (row & 7)) << 4));
            }
            #pragma unroll
            for (int i = 0; i < 4; ++i)
                #pragma unroll
                for (int j = 0; j < 4; ++j)
                    acc[i][j] = MFMA16x16(af[i], bfr[j], acc[i][j]);
        }
        __syncthreads();
    }

    if (MODE == 1) {
        #pragma unroll
        for (int i = 0; i < 4; ++i)
            #pragma unroll
            for (int j = 0; j < 4; ++j)
                #pragma unroll
                for (int r = 0; r < 4; ++r) {
                    int m = bm * 128 + rbase + i * 16 + (lane >> 4) * 4 + r;
                    int n = bn * 128 + cbase + j * 16 + (lane & 15);
                    C[(size_t)m * N + n] = acc[i][j][r];
                }
    } else {
        const int which = bn >> 3;    // 0=Q 1=K 2=V (128-col block never crosses)
        char* T = smem + w * 8192;    // per-wave 64x64 bf16, swizzled
        #pragma unroll
        for (int i = 0; i < 4; ++i)
            #pragma unroll
            for (int j = 0; j < 4; ++j)
                #pragma unroll
                for (int r = 0; r < 4; ++r) {
                    int mi = i * 16 + (lane >> 4) * 4 + r;
                    int ni = j * 16 + (lane & 15);
                    __bf16 v = (__bf16)acc[i][j][r];
                    if (which == 2)
                        *(__bf16*)(T + ni * 128 + ((mi * 2) ^ ((ni & 7) << 4))) = v;
                    else
                        *(__bf16*)(T + mi * 128 + ((ni * 2) ^ ((mi & 7) << 4))) = v;
                }
        #pragma unroll
        for (int it = 0; it < 8; ++it) {
            int id = it * 64 + lane;
            int row = id >> 3, cc = id & 7;
            bf16x8 v = *(const bf16x8*)(T + row * 128 + ((cc ^ (row & 7)) << 4));
            if (which == 2) {
                int n = bn * 128 + cbase + row;       // d-major row
                int m = bm * 128 + rbase + cc * 8;    // 8 consecutive l
                int b = m >> 11, l = m & (SEQ - 1);
                int h = (n & (DM - 1)) >> 6, d = n & 63;
                *(bf16x8*)(VTb + ((size_t)((b * NHEAD + h) * HD + d) * SEQ) + l) = v;
            } else {
                int m = bm * 128 + rbase + row;
                int n = bn * 128 + cbase + cc * 8;    // 8 consecutive d
                int b = m >> 11, l = m & (SEQ - 1);
                int h = (n & (DM - 1)) >> 6, d = n & 63;
                // fused RoPE (pairs are even/odd within the 8 consecutive d)
                int pb = tpos[l] * 32 + (d >> 1);
                float sc = (which == 0) ? 0.125f : 1.0f;   // fold 1/sqrt(64) into Q
                bf16x8 ov;
                #pragma unroll
                for (int jj = 0; jj < 4; ++jj) {
                    float cs = ct[pb + jj], sn = st[pb + jj];
                    float e = (float)v[2 * jj], dd = (float)v[2 * jj + 1];
                    ov[2 * jj]     = (__bf16)(sc * (cs * e - sn * dd));
                    ov[2 * jj + 1] = (__bf16)(sc * (sn * e + cs * dd));
                }
                __bf16* dst = which ? Kb : Qb;
                *(bf16x8*)(dst + ((size_t)(b * NHEAD + h) * SEQ + l) * HD + d) = ov;
            }
        }
    }
}

// ---------------- causal flash attention ----------------
// grid (16 qt-pairs, B*H); 4 waves; wave owns 16 q-rows; KV block = 64.
// Work-balanced: block p handles q-tiles {p, 31-p} -> 33 KV iterations each.
// Inner loop is the round-1-proven single-buffer stage->sync->compute->sync.
__global__ __launch_bounds__(256, 2)
void attn_kernel(const __bf16* __restrict__ Q, const __bf16* __restrict__ K,
                 const __bf16* __restrict__ VT, __bf16* __restrict__ O) {
    __shared__ __align__(16) char smem[24576];
    // layout: K @0 (8K) | V @8192 (8K) | P/Os @16384 (8K)
    char* Ks = smem;
    char* Vs = smem + 8192;
    const int lane = threadIdx.x & 63;
    const int w    = threadIdx.x >> 6;
    char* Ps = smem + 16384 + w * 2048;   // per-wave [16 q][64 j] bf16 swz
    const int pblk = blockIdx.x, bh = blockIdx.y;

    const __bf16* Qbh  = Q  + (size_t)bh * SEQ * HD;
    const __bf16* Kbh  = K  + (size_t)bh * SEQ * HD;
    const __bf16* VTbh = VT + (size_t)bh * HD * SEQ;
    const int b = bh >> 4, h = bh & 15;

    #pragma unroll 1
    for (int phase = 0; phase < 2; ++phase) {
        const int qb = phase ? (31 - pblk) : pblk;

        const int qrow = qb * 64 + w * 16 + (lane & 15);
        bf16x8 qf[2];
        qf[0] = *(const bf16x8*)(Qbh + (size_t)qrow * HD + (lane >> 4) * 8);
        qf[1] = *(const bf16x8*)(Qbh + (size_t)qrow * HD + 32 + (lane >> 4) * 8);

        f32x4 o[4] = {};
        float mrow[4] = {-1e30f, -1e30f, -1e30f, -1e30f};
        float lrow[4] = {0.f, 0.f, 0.f, 0.f};

        for (int kb = 0; kb <= qb; ++kb) {
            #pragma unroll
            for (int c = 0; c < 2; ++c) {
                int id = (c * 4 + w) * 64 + lane;
                int row = id >> 3, cc = id & 7;
                int sw = (cc ^ (row & 7)) << 3;
                gload16(Kbh + (size_t)(kb * 64 + row) * HD + sw, Ks + (c * 4 + w) * 1024);
                gload16(VTbh + (size_t)row * SEQ + kb * 64 + sw, Vs + (c * 4 + w) * 1024);
            }
            __syncthreads();

            f32x4 s[4];
            #pragma unroll
            for (int jt = 0; jt < 4; ++jt) {
                f32x4 z = {};
                #pragma unroll
                for (int ks = 0; ks < 2; ++ks) {
                    int row = jt * 16 + (lane & 15);
                    int c = ks * 4 + (lane >> 4);
                    bf16x8 kf = *(const bf16x8*)(Ks + row * 128 + ((c ^ (row & 7)) << 4));
                    z = MFMA16x16(qf[ks], kf, z);
                }
                s[jt] = z;
            }

            if (kb == qb) {
                #pragma unroll
                for (int jt = 0; jt < 4; ++jt) {
                    int j = kb * 64 + jt * 16 + (lane & 15);
                    #pragma unroll
                    for (int r = 0; r < 4; ++r) {
                        int i = qb * 64 + w * 16 + (lane >> 4) * 4 + r;
                        if (j > i) s[jt][r] = -1e30f;
                    }
                }
            }

            float alpha[4];
            #pragma unroll
            for (int r = 0; r < 4; ++r) {
                float mx = fmaxf(fmaxf(s[0][r], s[1][r]), fmaxf(s[2][r], s[3][r]));
                mx = fmaxf(mx, __shfl_xor(mx, 1));
                mx = fmaxf(mx, __shfl_xor(mx, 2));
                mx = fmaxf(mx, __shfl_xor(mx, 4));
                mx = fmaxf(mx, __shfl_xor(mx, 8));
                float mn = fmaxf(mrow[r], mx);
                alpha[r] = __expf(mrow[r] - mn);
                mrow[r] = mn;
                float rs = 0.f;
                #pragma unroll
                for (int jt = 0; jt < 4; ++jt) {
                    float pv = __expf(s[jt][r] - mn);
                    s[jt][r] = pv;
                    rs += pv;
                }
                rs += __shfl_xor(rs, 1);
                rs += __shfl_xor(rs, 2);
                rs += __shfl_xor(rs, 4);
                rs += __shfl_xor(rs, 8);
                lrow[r] = lrow[r] * alpha[r] + rs;
            }

            // P -> per-wave LDS (bf16, swizzled)
            #pragma unroll
            for (int jt = 0; jt < 4; ++jt)
                #pragma unroll
                for (int r = 0; r < 4; ++r) {
                    int qr = (lane >> 4) * 4 + r;
                    int jj = (jt * 16 + (lane & 15)) * 2;
                    *(__bf16*)(Ps + qr * 128 + (jj ^ ((qr & 7) << 4))) = (__bf16)s[jt][r];
                }

            #pragma unroll
            for (int dt = 0; dt < 4; ++dt)
                #pragma unroll
                for (int r = 0; r < 4; ++r)
                    o[dt][r] *= alpha[r];

            #pragma unroll
            for (int js = 0; js < 2; ++js) {
                int prow = lane & 15;
                int cb = js * 4 + (lane >> 4);
                bf16x8 pf = *(const bf16x8*)(Ps + prow * 128 + ((cb ^ (prow & 7)) << 4));
                #pragma unroll
                for (int dt = 0; dt < 4; ++dt) {
                    int vrow = dt * 16 + (lane & 15);
                    bf16x8 vf = *(const bf16x8*)(Vs + vrow * 128 + ((cb ^ (vrow & 7)) << 4));
                    o[dt] = MFMA16x16(pf, vf, o[dt]);
                }
            }
            __syncthreads();
        }

        float inv[4];
        #pragma unroll
        for (int r = 0; r < 4; ++r) inv[r] = 1.0f / lrow[r];

        // stage O tile [64 q][64 d] into the P region (each wave its own 2KB), then store
        char* Os = smem + 16384;
        #pragma unroll
        for (int dt = 0; dt < 4; ++dt)
            #pragma unroll
            for (int r = 0; r < 4; ++r) {
                int orow = w * 16 + (lane >> 4) * 4 + r;
                int oc = (dt * 16 + (lane & 15)) * 2;
                *(__bf16*)(Os + orow * 128 + (oc ^ ((orow & 7) << 4))) = (__bf16)(o[dt][r] * inv[r]);
            }
        __syncthreads();

        #pragma unroll
        for (int c = 0; c < 2; ++c) {
            int id = c * 256 + threadIdx.x;
            int row = id >> 3, cc = id & 7;
            bf16x8 v = *(const bf16x8*)(Os + row * 128 + ((cc ^ (row & 7)) << 4));
            *(bf16x8*)(O + (size_t)(b * SEQ + qb * 64 + row) * DM + h * HD + cc * 8) = v;
        }
        __syncthreads();   // Os fully consumed before next phase's Ps writes
    }
}

extern "C" void kernel_launch(void* const* d_in, const int* in_sizes, int n_in,
                              void* d_out, int out_size, void* d_ws, size_t ws_size,
                              hipStream_t stream) {
    const float* x  = (const float*)d_in[0];
    const float* wq = (const float*)d_in[1];
    const float* wk = (const float*)d_in[2];
    const float* wv = (const float*)d_in[3];
    const float* wo = (const float*)d_in[4];
    const int* tpos = (const int*)d_in[5];
    float* out = (float*)d_out;
    char* ws = (char*)d_ws;

    __bf16* xb   = (__bf16*)(ws);                        // 8 MB  [4096][1024]
    __bf16* wqkv = (__bf16*)(ws + (size_t)(8  << 20));   // 6 MB  [3072][1024]
    __bf16* wob  = (__bf16*)(ws + (size_t)(14 << 20));   // 2 MB  [1024][1024]
    __bf16* Qb   = (__bf16*)(ws + (size_t)(16 << 20));   // 8 MB  [32][2048][64]
    __bf16* Kb   = (__bf16*)(ws + (size_t)(24 << 20));   // 8 MB  [32][2048][64]
    __bf16* VTb  = (__bf16*)(ws + (size_t)(32 << 20));   // 8 MB  [32][64][2048]
    __bf16* Ob   = (__bf16*)(ws + (size_t)(40 << 20));   // 8 MB  [4096][1024]
    float* ct    = (float*)(ws + (size_t)(48 << 20));            // 256 KB
    float* st    = (float*)(ws + (size_t)(48 << 20) + 262144);   // 256 KB

    cvt_kernel<<<4096, 256, 0, stream>>>(x, xb, 4194304);
    cvt4_kernel<<<4096, 256, 0, stream>>>(wq, wk, wv, wo, wqkv, wob);
    rope_tab_kernel<<<256, 256, 0, stream>>>(ct, st);
    gemm_bt_kernel<0><<<dim3(24, 32), 256, 0, stream>>>(xb, wqkv, nullptr, Qb, Kb, VTb,
                                                        tpos, ct, st, 3072, 1024);
    attn_kernel<<<dim3(16, 32), 256, 0, stream>>>(Qb, Kb, VTb, Ob);
    gemm_bt_kernel<1><<<dim3(8, 32), 256, 0, stream>>>(Ob, wob, out, nullptr, nullptr, nullptr,
                                                       nullptr, nullptr, nullptr, 1024, 1024);
}

// Round 4
// 128.992 us; speedup vs baseline: 1.6052x; 1.1018x over previous
//
#include <hip/hip_runtime.h>
#include <stdint.h>
#include <stddef.h>

#define SEQ   2048
#define HD    64
#define DM    1024
#define NHEAD 16

typedef __bf16 bf16x8 __attribute__((ext_vector_type(8)));
typedef float  f32x4  __attribute__((ext_vector_type(4)));

#define MFMA16x16(a, b, c) __builtin_amdgcn_mfma_f32_16x16x32_bf16((a), (b), (c), 0, 0, 0)

__device__ __forceinline__ void gload16(const void* g, void* lds_uniform) {
    __builtin_amdgcn_global_load_lds(
        (const __attribute__((address_space(1))) uint32_t*)g,
        (__attribute__((address_space(3))) uint32_t*)lds_uniform, 16, 0, 0);
}

// ---------------- fp32 -> bf16 convert (x) ----------------
__global__ void cvt_kernel(const float* __restrict__ in, __bf16* __restrict__ out, int n) {
    int i = (blockIdx.x * blockDim.x + threadIdx.x) * 4;
    if (i >= n) return;
    const float4 v = *(const float4*)(in + i);
    __bf16 o[4] = {(__bf16)v.x, (__bf16)v.y, (__bf16)v.z, (__bf16)v.w};
    *(uint64_t*)(out + i) = *(const uint64_t*)o;
}

// ---------------- fp32 -> bf16 convert, all 4 weight mats in one launch -------------
__global__ void cvt4_kernel(const float* __restrict__ wq, const float* __restrict__ wk,
                            const float* __restrict__ wv, const float* __restrict__ wo,
                            __bf16* __restrict__ wqkv, __bf16* __restrict__ wob) {
    int g = blockIdx.x >> 10;                                 // 0..3
    int i = ((blockIdx.x & 1023) * 256 + threadIdx.x) * 4;    // 0..1048575
    const float* src = (g == 0) ? wq : (g == 1) ? wk : (g == 2) ? wv : wo;
    __bf16* dst = (g == 3) ? wob : (wqkv + (size_t)g * 1048576);
    const float4 v = *(const float4*)(src + i);
    __bf16 o[4] = {(__bf16)v.x, (__bf16)v.y, (__bf16)v.z, (__bf16)v.w};
    *(uint64_t*)(dst + i) = *(const uint64_t*)o;
}

// ---------------- rope tables: cos/sin[pos*32 + p] ----------------
__global__ void rope_tab_kernel(float* __restrict__ ct, float* __restrict__ st) {
    int i = blockIdx.x * blockDim.x + threadIdx.x;   // pos*32 + p, 65536 total
    int p = i & 31;
    int pos = i >> 5;
    float freq = expf(-(float)p * (logf(10000.0f) / 32.0f));  // theta^(-p/32)
    float ang = (float)pos * freq;
    ct[i] = cosf(ang);
    st[i] = sinf(ang);
}

// ---------------- GEMM: C[m][n] = sum_k A[m][k] * W[n][k]  (both K-contiguous) --------
// 128x128 tile, BK=64, 4 waves (2x2 of 64x64), global_load_lds(16B) staging with
// pre-swizzled source; LDS rows 128B, chunk XOR (row&7) swizzle -> conflict-free b128.
// MODE 0: N=3072 QKV; epilogue scatters bf16 to Q[B,H,L,64], K[B,H,L,64], VT[B,H,64,L]
//         via a per-wave LDS transpose tile; RoPE fused for Q,K.
//         Q gets scale 0.125*log2(e) so attention softmax can use exp2.
// MODE 1: plain fp32 C output.
template <int MODE>
__global__ __launch_bounds__(256, 2)
void gemm_bt_kernel(const __bf16* __restrict__ A, const __bf16* __restrict__ W,
                    float* __restrict__ C, __bf16* __restrict__ Qb,
                    __bf16* __restrict__ Kb, __bf16* __restrict__ VTb,
                    const int* __restrict__ tpos, const float* __restrict__ ct,
                    const float* __restrict__ st, int N, int K) {
    __shared__ __align__(16) char smem[32768];
    char* As = smem;
    char* Bs = smem + 16384;
    const int lane = threadIdx.x & 63;
    const int w    = threadIdx.x >> 6;
    const int bn = blockIdx.x, bm = blockIdx.y;
    const int rbase = (w >> 1) * 64;
    const int cbase = (w & 1) * 64;

    f32x4 acc[4][4] = {};

    const int kt_iters = K >> 6;
    for (int kt = 0; kt < kt_iters; ++kt) {
        #pragma unroll
        for (int c = 0; c < 4; ++c) {
            int id = (c * 4 + w) * 64 + lane;
            int row = id >> 3, cc = id & 7;
            int koff = kt * 64 + ((cc ^ (row & 7)) << 3);
            gload16(A + (size_t)(bm * 128 + row) * K + koff, As + (c * 4 + w) * 1024);
            gload16(W + (size_t)(bn * 128 + row) * K + koff, Bs + (c * 4 + w) * 1024);
        }
        __syncthreads();
        #pragma unroll
        for (int ks = 0; ks < 2; ++ks) {
            bf16x8 af[4], bfr[4];
            #pragma unroll
            for (int i = 0; i < 4; ++i) {
                int row = rbase + i * 16 + (lane & 15);
                int c = ks * 4 + (lane >> 4);
                af[i] = *(const bf16x8*)(As + row * 128 + ((c ^ (row & 7)) << 4));
            }
            #pragma unroll
            for (int j = 0; j < 4; ++j) {
                int row = cbase + j * 16 + (lane & 15);
                int c = ks * 4 + (lane >> 4);
                bfr[j] = *(const bf16x8*)(Bs + row * 128 + ((c ^ (row & 7)) << 4));
            }
            #pragma unroll
            for (int i = 0; i < 4; ++i)
                #pragma unroll
                for (int j = 0; j < 4; ++j)
                    acc[i][j] = MFMA16x16(af[i], bfr[j], acc[i][j]);
        }
        __syncthreads();
    }

    if (MODE == 1) {
        #pragma unroll
        for (int i = 0; i < 4; ++i)
            #pragma unroll
            for (int j = 0; j < 4; ++j)
                #pragma unroll
                for (int r = 0; r < 4; ++r) {
                    int m = bm * 128 + rbase + i * 16 + (lane >> 4) * 4 + r;
                    int n = bn * 128 + cbase + j * 16 + (lane & 15);
                    C[(size_t)m * N + n] = acc[i][j][r];
                }
    } else {
        const int which = bn >> 3;    // 0=Q 1=K 2=V (128-col block never crosses)
        char* T = smem + w * 8192;    // per-wave 64x64 bf16, swizzled
        #pragma unroll
        for (int i = 0; i < 4; ++i)
            #pragma unroll
            for (int j = 0; j < 4; ++j)
                #pragma unroll
                for (int r = 0; r < 4; ++r) {
                    int mi = i * 16 + (lane >> 4) * 4 + r;
                    int ni = j * 16 + (lane & 15);
                    __bf16 v = (__bf16)acc[i][j][r];
                    if (which == 2)
                        *(__bf16*)(T + ni * 128 + ((mi * 2) ^ ((ni & 7) << 4))) = v;
                    else
                        *(__bf16*)(T + mi * 128 + ((ni * 2) ^ ((mi & 7) << 4))) = v;
                }
        #pragma unroll
        for (int it = 0; it < 8; ++it) {
            int id = it * 64 + lane;
            int row = id >> 3, cc = id & 7;
            bf16x8 v = *(const bf16x8*)(T + row * 128 + ((cc ^ (row & 7)) << 4));
            if (which == 2) {
                int n = bn * 128 + cbase + row;       // d-major row
                int m = bm * 128 + rbase + cc * 8;    // 8 consecutive l
                int b = m >> 11, l = m & (SEQ - 1);
                int h = (n & (DM - 1)) >> 6, d = n & 63;
                *(bf16x8*)(VTb + ((size_t)((b * NHEAD + h) * HD + d) * SEQ) + l) = v;
            } else {
                int m = bm * 128 + rbase + row;
                int n = bn * 128 + cbase + cc * 8;    // 8 consecutive d
                int b = m >> 11, l = m & (SEQ - 1);
                int h = (n & (DM - 1)) >> 6, d = n & 63;
                // fused RoPE (pairs are even/odd within the 8 consecutive d)
                int pb = tpos[l] * 32 + (d >> 1);
                // Q: fold 1/sqrt(64) * log2(e) so softmax can use exp2
                float sc = (which == 0) ? 0.18033688011112042f : 1.0f;
                bf16x8 ov;
                #pragma unroll
                for (int jj = 0; jj < 4; ++jj) {
                    float cs = ct[pb + jj], sn = st[pb + jj];
                    float e = (float)v[2 * jj], dd = (float)v[2 * jj + 1];
                    ov[2 * jj]     = (__bf16)(sc * (cs * e - sn * dd));
                    ov[2 * jj + 1] = (__bf16)(sc * (sn * e + cs * dd));
                }
                __bf16* dst = which ? Kb : Qb;
                *(bf16x8*)(dst + ((size_t)(b * NHEAD + h) * SEQ + l) * HD + d) = ov;
            }
        }
    }
}

// ---------------- causal flash attention ----------------
// 512 linear blocks, XCD-pinned: xcd = bid&7 owns 4 heads (KV 2MB fits per-XCD L2).
// Block handles q-tiles {p, 31-p} (33 balanced KV iterations). 4 waves, 16 q-rows/wave.
// K/V double-buffered: reg-staged prefetch for kb+1 issued before compute of kb,
// swizzled ds_write after, ONE __syncthreads per iteration (no exposed vmcnt drain).
// Swapped QK^T: mfma(kf, qf) puts a full S-row slice in each lane -> softmax is a
// register tree + 2 shfl_xor, exp2-domain (log2e folded into Q scale).
__global__ __launch_bounds__(256, 2)
void attn_kernel(const __bf16* __restrict__ Q, const __bf16* __restrict__ K,
                 const __bf16* __restrict__ VT, __bf16* __restrict__ O) {
    __shared__ __align__(16) char smem[40960];
    // buf0: K@0 V@8192 | buf1: K@16384 V@24576 | Ps/Os @32768 (8K)
    const int lane = threadIdx.x & 63;
    const int w    = threadIdx.x >> 6;
    const int tid  = threadIdx.x;
    char* Ps = smem + 32768 + w * 2048;   // per-wave [16 q][64 j] bf16 swz

    const int bid  = blockIdx.x;
    const int xcd  = bid & 7;
    const int sl   = bid >> 3;            // 0..63 consecutive on this XCD
    const int bh   = xcd * 4 + (sl >> 4); // 4 heads per XCD
    const int pblk = sl & 15;

    const __bf16* Qbh  = Q  + (size_t)bh * SEQ * HD;
    const __bf16* Kbh  = K  + (size_t)bh * SEQ * HD;
    const __bf16* VTbh = VT + (size_t)bh * HD * SEQ;
    const int b = bh >> 4, h = bh & 15;

    #pragma unroll 1
    for (int phase = 0; phase < 2; ++phase) {
        const int qb = phase ? (31 - pblk) : pblk;

        // prologue: stage tile 0 into buf0 (pre-swizzled source, linear LDS dest)
        #pragma unroll
        for (int c = 0; c < 2; ++c) {
            int id = (c * 4 + w) * 64 + lane;
            int row = id >> 3, cc = id & 7;
            int sw = (cc ^ (row & 7)) << 3;
            gload16(Kbh + (size_t)row * HD + sw, smem + (c * 4 + w) * 1024);
            gload16(VTbh + (size_t)row * SEQ + sw, smem + 8192 + (c * 4 + w) * 1024);
        }

        const int qrow = qb * 64 + w * 16 + (lane & 15);
        bf16x8 qf[2];
        qf[0] = *(const bf16x8*)(Qbh + (size_t)qrow * HD + (lane >> 4) * 8);
        qf[1] = *(const bf16x8*)(Qbh + (size_t)qrow * HD + 32 + (lane >> 4) * 8);

        f32x4 o[4] = {};
        float mrow = -1e30f;   // per-lane: this lane's q-row = lane&15 (of wave's 16)
        float lrow = 0.f;

        int cur = 0;
        __syncthreads();   // drains prologue gload_lds (vmcnt0) for all waves

        for (int kb = 0; kb <= qb; ++kb) {
            // issue next tile's loads to REGISTERS early (latency hides under compute)
            bf16x8 kreg[2], vreg[2];
            if (kb < qb) {
                #pragma unroll
                for (int c = 0; c < 2; ++c) {
                    int id = c * 256 + tid;
                    int row = id >> 3, cc = id & 7;
                    kreg[c] = *(const bf16x8*)(Kbh + (size_t)((kb + 1) * 64 + row) * HD + cc * 8);
                    vreg[c] = *(const bf16x8*)(VTbh + (size_t)row * SEQ + (kb + 1) * 64 + cc * 8);
                }
            }

            char* Ks = smem + cur * 16384;
            char* Vs = Ks + 8192;

            // swapped QK^T: S^T tile. lane holds row i = lane&15 (wave-local),
            // j = kb*64 + jt*16 + (lane>>4)*4 + r
            f32x4 s[4];
            #pragma unroll
            for (int jt = 0; jt < 4; ++jt) {
                f32x4 z = {};
                #pragma unroll
                for (int ks = 0; ks < 2; ++ks) {
                    int row = jt * 16 + (lane & 15);
                    int c = ks * 4 + (lane >> 4);
                    bf16x8 kf = *(const bf16x8*)(Ks + row * 128 + ((c ^ (row & 7)) << 4));
                    z = MFMA16x16(kf, qf[ks], z);
                }
                s[jt] = z;
            }

            if (kb == qb) {
                int i = qb * 64 + w * 16 + (lane & 15);
                #pragma unroll
                for (int jt = 0; jt < 4; ++jt)
                    #pragma unroll
                    for (int r = 0; r < 4; ++r) {
                        int j = kb * 64 + jt * 16 + (lane >> 4) * 4 + r;
                        if (j > i) s[jt][r] = -1e30f;
                    }
            }

            // per-lane row softmax (exp2 domain)
            float pmax = fmaxf(fmaxf(fmaxf(s[0][0], s[0][1]), fmaxf(s[0][2], s[0][3])),
                               fmaxf(fmaxf(s[1][0], s[1][1]), fmaxf(s[1][2], s[1][3])));
            pmax = fmaxf(pmax,
                   fmaxf(fmaxf(fmaxf(s[2][0], s[2][1]), fmaxf(s[2][2], s[2][3])),
                         fmaxf(fmaxf(s[3][0], s[3][1]), fmaxf(s[3][2], s[3][3]))));
            pmax = fmaxf(pmax, __shfl_xor(pmax, 16));
            pmax = fmaxf(pmax, __shfl_xor(pmax, 32));
            float mn = fmaxf(mrow, pmax);
            float alpha = exp2f(mrow - mn);
            mrow = mn;
            float rs = 0.f;
            #pragma unroll
            for (int jt = 0; jt < 4; ++jt)
                #pragma unroll
                for (int r = 0; r < 4; ++r) {
                    float pv = exp2f(s[jt][r] - mn);
                    s[jt][r] = pv;
                    rs += pv;
                }
            rs += __shfl_xor(rs, 16);
            rs += __shfl_xor(rs, 32);
            lrow = lrow * alpha + rs;

            // P -> per-wave LDS (bf16, swizzled): row qr = lane&15
            {
                int qr = lane & 15;
                int swrow = (qr & 7) << 4;
                #pragma unroll
                for (int jt = 0; jt < 4; ++jt)
                    #pragma unroll
                    for (int r = 0; r < 4; ++r) {
                        int jj = (jt * 16 + (lane >> 4) * 4 + r) * 2;
                        *(__bf16*)(Ps + qr * 128 + (jj ^ swrow)) = (__bf16)s[jt][r];
                    }
            }

            // rescale O: needs alpha of row (lane>>4)*4+r -> broadcast from lanes 0..15
            float ar[4];
            #pragma unroll
            for (int r = 0; r < 4; ++r) ar[r] = __shfl(alpha, (lane >> 4) * 4 + r);
            #pragma unroll
            for (int dt = 0; dt < 4; ++dt)
                #pragma unroll
                for (int r = 0; r < 4; ++r)
                    o[dt][r] *= ar[r];

            // PV: O[q][d] += P[q][j] * VT[d][j]
            #pragma unroll
            for (int js = 0; js < 2; ++js) {
                int prow = lane & 15;
                int cb = js * 4 + (lane >> 4);
                bf16x8 pf = *(const bf16x8*)(Ps + prow * 128 + ((cb ^ (prow & 7)) << 4));
                #pragma unroll
                for (int dt = 0; dt < 4; ++dt) {
                    int vrow = dt * 16 + (lane & 15);
                    bf16x8 vf = *(const bf16x8*)(Vs + vrow * 128 + ((cb ^ (vrow & 7)) << 4));
                    o[dt] = MFMA16x16(pf, vf, o[dt]);
                }
            }

            // write prefetched tile into the OTHER buffer (vmcnt waits auto-inserted)
            if (kb < qb) {
                char* Kn = smem + (cur ^ 1) * 16384;
                char* Vn = Kn + 8192;
                #pragma unroll
                for (int c = 0; c < 2; ++c) {
                    int id = c * 256 + tid;
                    int row = id >> 3, cc = id & 7;
                    int sw = (cc ^ (row & 7)) << 4;
                    *(bf16x8*)(Kn + row * 128 + sw) = kreg[c];
                    *(bf16x8*)(Vn + row * 128 + sw) = vreg[c];
                }
            }
            __syncthreads();   // writes visible; reads of cur done; queue already drained
            cur ^= 1;
        }

        // final 1/l per accumulator row (broadcast l from lanes 0..15)
        float linv[4];
        #pragma unroll
        for (int r = 0; r < 4; ++r) {
            float lr = __shfl(lrow, (lane >> 4) * 4 + r);
            linv[r] = 1.0f / lr;
        }

        // stage O tile [64 q][64 d] into the P region (each wave its own 2KB), then store
        char* Os = smem + 32768;
        #pragma unroll
        for (int dt = 0; dt < 4; ++dt)
            #pragma unroll
            for (int r = 0; r < 4; ++r) {
                int orow = w * 16 + (lane >> 4) * 4 + r;
                int oc = (dt * 16 + (lane & 15)) * 2;
                *(__bf16*)(Os + orow * 128 + (oc ^ ((orow & 7) << 4))) = (__bf16)(o[dt][r] * linv[r]);
            }
        __syncthreads();

        #pragma unroll
        for (int c = 0; c < 2; ++c) {
            int id = c * 256 + tid;
            int row = id >> 3, cc = id & 7;
            bf16x8 v = *(const bf16x8*)(Os + row * 128 + ((cc ^ (row & 7)) << 4));
            *(bf16x8*)(O + (size_t)(b * SEQ + qb * 64 + row) * DM + h * HD + cc * 8) = v;
        }
        __syncthreads();   // Os fully consumed before next phase reuses the region
    }
}

extern "C" void kernel_launch(void* const* d_in, const int* in_sizes, int n_in,
                              void* d_out, int out_size, void* d_ws, size_t ws_size,
                              hipStream_t stream) {
    const float* x  = (const float*)d_in[0];
    const float* wq = (const float*)d_in[1];
    const float* wk = (const float*)d_in[2];
    const float* wv = (const float*)d_in[3];
    const float* wo = (const float*)d_in[4];
    const int* tpos = (const int*)d_in[5];
    float* out = (float*)d_out;
    char* ws = (char*)d_ws;

    __bf16* xb   = (__bf16*)(ws);                        // 8 MB  [4096][1024]
    __bf16* wqkv = (__bf16*)(ws + (size_t)(8  << 20));   // 6 MB  [3072][1024]
    __bf16* wob  = (__bf16*)(ws + (size_t)(14 << 20));   // 2 MB  [1024][1024]
    __bf16* Qb   = (__bf16*)(ws + (size_t)(16 << 20));   // 8 MB  [32][2048][64]
    __bf16* Kb   = (__bf16*)(ws + (size_t)(24 << 20));   // 8 MB  [32][2048][64]
    __bf16* VTb  = (__bf16*)(ws + (size_t)(32 << 20));   // 8 MB  [32][64][2048]
    __bf16* Ob   = (__bf16*)(ws + (size_t)(40 << 20));   // 8 MB  [4096][1024]
    float* ct    = (float*)(ws + (size_t)(48 << 20));            // 256 KB
    float* st    = (float*)(ws + (size_t)(48 << 20) + 262144);   // 256 KB

    cvt_kernel<<<4096, 256, 0, stream>>>(x, xb, 4194304);
    cvt4_kernel<<<4096, 256, 0, stream>>>(wq, wk, wv, wo, wqkv, wob);
    rope_tab_kernel<<<256, 256, 0, stream>>>(ct, st);
    gemm_bt_kernel<0><<<dim3(24, 32), 256, 0, stream>>>(xb, wqkv, nullptr, Qb, Kb, VTb,
                                                        tpos, ct, st, 3072, 1024);
    attn_kernel<<<512, 256, 0, stream>>>(Qb, Kb, VTb, Ob);
    gemm_bt_kernel<1><<<dim3(8, 32), 256, 0, stream>>>(Ob, wob, out, nullptr, nullptr, nullptr,
                                                       nullptr, nullptr, nullptr, 1024, 1024);
}

// Round 5
// 115.924 us; speedup vs baseline: 1.7861x; 1.1127x over previous
//
#include <hip/hip_runtime.h>
#include <stdint.h>
#include <stddef.h>

#define SEQ   2048
#define HD    64
#define DM    1024
#define NHEAD 16

typedef __bf16 bf16x8 __attribute__((ext_vector_type(8)));
typedef __bf16 bf16x4 __attribute__((ext_vector_type(4)));
typedef float  f32x4  __attribute__((ext_vector_type(4)));

#define MFMA16x16(a, b, c) __builtin_amdgcn_mfma_f32_16x16x32_bf16((a), (b), (c), 0, 0, 0)

__device__ __forceinline__ void gload16(const void* g, void* lds_uniform) {
    __builtin_amdgcn_global_load_lds(
        (const __attribute__((address_space(1))) uint32_t*)g,
        (__attribute__((address_space(3))) uint32_t*)lds_uniform, 16, 0, 0);
}

// ---------------- fp32 -> bf16 convert (x) ----------------
__global__ void cvt_kernel(const float* __restrict__ in, __bf16* __restrict__ out, int n) {
    int i = (blockIdx.x * blockDim.x + threadIdx.x) * 4;
    if (i >= n) return;
    const float4 v = *(const float4*)(in + i);
    __bf16 o[4] = {(__bf16)v.x, (__bf16)v.y, (__bf16)v.z, (__bf16)v.w};
    *(uint64_t*)(out + i) = *(const uint64_t*)o;
}

// ---------------- fp32 -> bf16 convert, all 4 weight mats in one launch -------------
__global__ void cvt4_kernel(const float* __restrict__ wq, const float* __restrict__ wk,
                            const float* __restrict__ wv, const float* __restrict__ wo,
                            __bf16* __restrict__ wqkv, __bf16* __restrict__ wob) {
    int g = blockIdx.x >> 10;                                 // 0..3
    int i = ((blockIdx.x & 1023) * 256 + threadIdx.x) * 4;    // 0..1048575
    const float* src = (g == 0) ? wq : (g == 1) ? wk : (g == 2) ? wv : wo;
    __bf16* dst = (g == 3) ? wob : (wqkv + (size_t)g * 1048576);
    const float4 v = *(const float4*)(src + i);
    __bf16 o[4] = {(__bf16)v.x, (__bf16)v.y, (__bf16)v.z, (__bf16)v.w};
    *(uint64_t*)(dst + i) = *(const uint64_t*)o;
}

// ---------------- rope tables: cos/sin[pos*32 + p] ----------------
__global__ void rope_tab_kernel(float* __restrict__ ct, float* __restrict__ st) {
    int i = blockIdx.x * blockDim.x + threadIdx.x;   // pos*32 + p, 65536 total
    int p = i & 31;
    int pos = i >> 5;
    float freq = expf(-(float)p * (logf(10000.0f) / 32.0f));  // theta^(-p/32)
    float ang = (float)pos * freq;
    ct[i] = cosf(ang);
    st[i] = sinf(ang);
}

// ---------------- GEMM: C[m][n] = sum_k A[m][k] * W[n][k]  (both K-contiguous) --------
// 128x128 tile, BK=64, 4 waves (2x2 of 64x64), global_load_lds(16B) staging with
// pre-swizzled source; LDS rows 128B, chunk XOR (row&7) swizzle -> conflict-free b128.
// MODE 0: N=3072 QKV; epilogue scatters bf16 to Q[B,H,L,64], K[B,H,L,64], VT[B,H,64,L]
//         via a per-wave LDS transpose tile; RoPE fused for Q,K.
//         Q gets scale 0.125*log2(e) so attention softmax can use exp2.
// MODE 1: plain fp32 C output.
template <int MODE>
__global__ __launch_bounds__(256, 2)
void gemm_bt_kernel(const __bf16* __restrict__ A, const __bf16* __restrict__ W,
                    float* __restrict__ C, __bf16* __restrict__ Qb,
                    __bf16* __restrict__ Kb, __bf16* __restrict__ VTb,
                    const int* __restrict__ tpos, const float* __restrict__ ct,
                    const float* __restrict__ st, int N, int K) {
    __shared__ __align__(16) char smem[32768];
    char* As = smem;
    char* Bs = smem + 16384;
    const int lane = threadIdx.x & 63;
    const int w    = threadIdx.x >> 6;
    const int bn = blockIdx.x, bm = blockIdx.y;
    const int rbase = (w >> 1) * 64;
    const int cbase = (w & 1) * 64;

    f32x4 acc[4][4] = {};

    const int kt_iters = K >> 6;
    for (int kt = 0; kt < kt_iters; ++kt) {
        #pragma unroll
        for (int c = 0; c < 4; ++c) {
            int id = (c * 4 + w) * 64 + lane;
            int row = id >> 3, cc = id & 7;
            int koff = kt * 64 + ((cc ^ (row & 7)) << 3);
            gload16(A + (size_t)(bm * 128 + row) * K + koff, As + (c * 4 + w) * 1024);
            gload16(W + (size_t)(bn * 128 + row) * K + koff, Bs + (c * 4 + w) * 1024);
        }
        __syncthreads();
        #pragma unroll
        for (int ks = 0; ks < 2; ++ks) {
            bf16x8 af[4], bfr[4];
            #pragma unroll
            for (int i = 0; i < 4; ++i) {
                int row = rbase + i * 16 + (lane & 15);
                int c = ks * 4 + (lane >> 4);
                af[i] = *(const bf16x8*)(As + row * 128 + ((c ^ (row & 7)) << 4));
            }
            #pragma unroll
            for (int j = 0; j < 4; ++j) {
                int row = cbase + j * 16 + (lane & 15);
                int c = ks * 4 + (lane >> 4);
                bfr[j] = *(const bf16x8*)(Bs + row * 128 + ((c ^ (row & 7)) << 4));
            }
            #pragma unroll
            for (int i = 0; i < 4; ++i)
                #pragma unroll
                for (int j = 0; j < 4; ++j)
                    acc[i][j] = MFMA16x16(af[i], bfr[j], acc[i][j]);
        }
        __syncthreads();
    }

    if (MODE == 1) {
        #pragma unroll
        for (int i = 0; i < 4; ++i)
            #pragma unroll
            for (int j = 0; j < 4; ++j)
                #pragma unroll
                for (int r = 0; r < 4; ++r) {
                    int m = bm * 128 + rbase + i * 16 + (lane >> 4) * 4 + r;
                    int n = bn * 128 + cbase + j * 16 + (lane & 15);
                    C[(size_t)m * N + n] = acc[i][j][r];
                }
    } else {
        const int which = bn >> 3;    // 0=Q 1=K 2=V (128-col block never crosses)
        char* T = smem + w * 8192;    // per-wave 64x64 bf16, swizzled
        #pragma unroll
        for (int i = 0; i < 4; ++i)
            #pragma unroll
            for (int j = 0; j < 4; ++j)
                #pragma unroll
                for (int r = 0; r < 4; ++r) {
                    int mi = i * 16 + (lane >> 4) * 4 + r;
                    int ni = j * 16 + (lane & 15);
                    __bf16 v = (__bf16)acc[i][j][r];
                    if (which == 2)
                        *(__bf16*)(T + ni * 128 + ((mi * 2) ^ ((ni & 7) << 4))) = v;
                    else
                        *(__bf16*)(T + mi * 128 + ((ni * 2) ^ ((mi & 7) << 4))) = v;
                }
        #pragma unroll
        for (int it = 0; it < 8; ++it) {
            int id = it * 64 + lane;
            int row = id >> 3, cc = id & 7;
            bf16x8 v = *(const bf16x8*)(T + row * 128 + ((cc ^ (row & 7)) << 4));
            if (which == 2) {
                int n = bn * 128 + cbase + row;       // d-major row
                int m = bm * 128 + rbase + cc * 8;    // 8 consecutive l
                int b = m >> 11, l = m & (SEQ - 1);
                int h = (n & (DM - 1)) >> 6, d = n & 63;
                *(bf16x8*)(VTb + ((size_t)((b * NHEAD + h) * HD + d) * SEQ) + l) = v;
            } else {
                int m = bm * 128 + rbase + row;
                int n = bn * 128 + cbase + cc * 8;    // 8 consecutive d
                int b = m >> 11, l = m & (SEQ - 1);
                int h = (n & (DM - 1)) >> 6, d = n & 63;
                // fused RoPE (pairs are even/odd within the 8 consecutive d)
                int pb = tpos[l] * 32 + (d >> 1);
                // Q: fold 1/sqrt(64) * log2(e) so softmax can use exp2
                float sc = (which == 0) ? 0.18033688011112042f : 1.0f;
                bf16x8 ov;
                #pragma unroll
                for (int jj = 0; jj < 4; ++jj) {
                    float cs = ct[pb + jj], sn = st[pb + jj];
                    float e = (float)v[2 * jj], dd = (float)v[2 * jj + 1];
                    ov[2 * jj]     = (__bf16)(sc * (cs * e - sn * dd));
                    ov[2 * jj + 1] = (__bf16)(sc * (sn * e + cs * dd));
                }
                __bf16* dst = which ? Kb : Qb;
                *(bf16x8*)(dst + ((size_t)(b * NHEAD + h) * SEQ + l) * HD + d) = ov;
            }
        }
    }
}

// ---------------- causal flash attention ----------------
// 1024 blocks (one 64-row q-tile each), XCD-pinned: xcd=bid&7 owns 4 heads
// (KV 2MB fits per-XCD L2). Within an XCD, qb DESCENDING so long blocks start
// first (greedy LPT packing). 4 blocks/CU by LDS (40960B), 16 waves/CU.
// K/V double-buffered: reg-staged prefetch issued before compute, swizzled
// ds_write after, ONE __syncthreads per iteration.
// Swapped QK^T: lane holds a full S-row slice -> softmax is a register tree.
// T13 defer-max: skip max-reduce + O-rescale unless __all(pmax<=mrow+8) fails.
// l-sum kept as per-lane partial, reduced once after the loop.
__global__ __launch_bounds__(256, 4)
void attn_kernel(const __bf16* __restrict__ Q, const __bf16* __restrict__ K,
                 const __bf16* __restrict__ VT, __bf16* __restrict__ O) {
    __shared__ __align__(16) char smem[40960];
    // buf0: K@0 V@8192 | buf1: K@16384 V@24576 | Ps/Os @32768 (8K)
    const int lane = threadIdx.x & 63;
    const int w    = threadIdx.x >> 6;
    const int tid  = threadIdx.x;
    char* Ps = smem + 32768 + w * 2048;   // per-wave [16 q][64 j] bf16 swz

    const int bid = blockIdx.x;
    const int xcd = bid & 7;
    const int idx = bid >> 3;             // 0..127 per XCD
    const int bh  = xcd * 4 + (idx & 3);  // 4 heads per XCD
    const int qb  = 31 - (idx >> 2);      // descending: longest first

    const __bf16* Qbh  = Q  + (size_t)bh * SEQ * HD;
    const __bf16* Kbh  = K  + (size_t)bh * SEQ * HD;
    const __bf16* VTbh = VT + (size_t)bh * HD * SEQ;
    const int b = bh >> 4, h = bh & 15;

    // prologue: stage tile 0 into buf0 (pre-swizzled source, linear LDS dest)
    #pragma unroll
    for (int c = 0; c < 2; ++c) {
        int id = (c * 4 + w) * 64 + lane;
        int row = id >> 3, cc = id & 7;
        int sw = (cc ^ (row & 7)) << 3;
        gload16(Kbh + (size_t)row * HD + sw, smem + (c * 4 + w) * 1024);
        gload16(VTbh + (size_t)row * SEQ + sw, smem + 8192 + (c * 4 + w) * 1024);
    }

    const int qrow = qb * 64 + w * 16 + (lane & 15);
    bf16x8 qf[2];
    qf[0] = *(const bf16x8*)(Qbh + (size_t)qrow * HD + (lane >> 4) * 8);
    qf[1] = *(const bf16x8*)(Qbh + (size_t)qrow * HD + 32 + (lane >> 4) * 8);

    f32x4 o[4] = {};
    float mrow = -1e30f;   // row max-so-far for row lane&15 (wave-uniform per row)
    float lrow = 0.f;      // PER-LANE partial sum (reduced after the loop)

    int cur = 0;
    __syncthreads();   // drains prologue gload_lds for all waves

    for (int kb = 0; kb <= qb; ++kb) {
        // issue next tile's loads to REGISTERS early (latency hides under compute)
        bf16x8 kreg[2], vreg[2];
        if (kb < qb) {
            #pragma unroll
            for (int c = 0; c < 2; ++c) {
                int id = c * 256 + tid;
                int row = id >> 3, cc = id & 7;
                kreg[c] = *(const bf16x8*)(Kbh + (size_t)((kb + 1) * 64 + row) * HD + cc * 8);
                vreg[c] = *(const bf16x8*)(VTbh + (size_t)row * SEQ + (kb + 1) * 64 + cc * 8);
            }
        }

        char* Ks = smem + cur * 16384;
        char* Vs = Ks + 8192;

        // swapped QK^T: lane holds row i = lane&15 (wave-local),
        // j = kb*64 + jt*16 + (lane>>4)*4 + r
        f32x4 s[4];
        #pragma unroll
        for (int jt = 0; jt < 4; ++jt) {
            f32x4 z = {};
            #pragma unroll
            for (int ks = 0; ks < 2; ++ks) {
                int row = jt * 16 + (lane & 15);
                int c = ks * 4 + (lane >> 4);
                bf16x8 kf = *(const bf16x8*)(Ks + row * 128 + ((c ^ (row & 7)) << 4));
                z = MFMA16x16(kf, qf[ks], z);
            }
            s[jt] = z;
        }

        if (kb == qb) {
            int i = qb * 64 + w * 16 + (lane & 15);
            #pragma unroll
            for (int jt = 0; jt < 4; ++jt)
                #pragma unroll
                for (int r = 0; r < 4; ++r) {
                    int j = kb * 64 + jt * 16 + (lane >> 4) * 4 + r;
                    if (j > i) s[jt][r] = -1e30f;
                }
        }

        // per-lane partial max over this lane's 16 values
        float pmax = fmaxf(fmaxf(fmaxf(s[0][0], s[0][1]), fmaxf(s[0][2], s[0][3])),
                           fmaxf(fmaxf(s[1][0], s[1][1]), fmaxf(s[1][2], s[1][3])));
        pmax = fmaxf(pmax,
               fmaxf(fmaxf(fmaxf(s[2][0], s[2][1]), fmaxf(s[2][2], s[2][3])),
                     fmaxf(fmaxf(s[3][0], s[3][1]), fmaxf(s[3][2], s[3][3]))));

        // T13 defer-max: only do the full reduce + rescale when needed (rare)
        if (!__all(pmax <= mrow + 8.0f)) {
            pmax = fmaxf(pmax, __shfl_xor(pmax, 16));
            pmax = fmaxf(pmax, __shfl_xor(pmax, 32));
            float mn = fmaxf(mrow, pmax);
            float alpha = exp2f(mrow - mn);
            mrow = mn;
            lrow *= alpha;                       // per-lane partial, alpha row-uniform
            float ar[4];
            #pragma unroll
            for (int r = 0; r < 4; ++r) ar[r] = __shfl(alpha, (lane >> 4) * 4 + r);
            #pragma unroll
            for (int dt = 0; dt < 4; ++dt)
                #pragma unroll
                for (int r = 0; r < 4; ++r)
                    o[dt][r] *= ar[r];
        }

        // exp2, accumulate per-lane partial sum, pack 4 bf16 -> one ds_write_b64
        {
            int qr = lane & 15;
            int swrow = (qr & 7) << 4;
            float rs = 0.f;
            #pragma unroll
            for (int jt = 0; jt < 4; ++jt) {
                bf16x4 pk;
                #pragma unroll
                for (int r = 0; r < 4; ++r) {
                    float pv = exp2f(s[jt][r] - mrow);
                    rs += pv;
                    pk[r] = (__bf16)pv;
                }
                int jj = (jt * 16 + (lane >> 4) * 4) * 2;
                *(bf16x4*)(Ps + qr * 128 + (jj ^ swrow)) = pk;
            }
            lrow += rs;
        }

        // PV: O[q][d] += P[q][j] * VT[d][j]
        #pragma unroll
        for (int js = 0; js < 2; ++js) {
            int prow = lane & 15;
            int cb = js * 4 + (lane >> 4);
            bf16x8 pf = *(const bf16x8*)(Ps + prow * 128 + ((cb ^ (prow & 7)) << 4));
            #pragma unroll
            for (int dt = 0; dt < 4; ++dt) {
                int vrow = dt * 16 + (lane & 15);
                bf16x8 vf = *(const bf16x8*)(Vs + vrow * 128 + ((cb ^ (vrow & 7)) << 4));
                o[dt] = MFMA16x16(pf, vf, o[dt]);
            }
        }

        // write prefetched tile into the OTHER buffer (vmcnt waits auto-inserted)
        if (kb < qb) {
            char* Kn = smem + (cur ^ 1) * 16384;
            char* Vn = Kn + 8192;
            #pragma unroll
            for (int c = 0; c < 2; ++c) {
                int id = c * 256 + tid;
                int row = id >> 3, cc = id & 7;
                int sw = (cc ^ (row & 7)) << 4;
                *(bf16x8*)(Kn + row * 128 + sw) = kreg[c];
                *(bf16x8*)(Vn + row * 128 + sw) = vreg[c];
            }
        }
        __syncthreads();
        cur ^= 1;
    }

    // reduce per-lane partial l over the 4 lanes of each row, then broadcast
    lrow += __shfl_xor(lrow, 16);
    lrow += __shfl_xor(lrow, 32);
    float linv[4];
    #pragma unroll
    for (int r = 0; r < 4; ++r) {
        float lr = __shfl(lrow, (lane >> 4) * 4 + r);
        linv[r] = 1.0f / lr;
    }

    // stage O tile [64 q][64 d] into the P region (each wave its own 2KB), then store
    char* Os = smem + 32768;
    #pragma unroll
    for (int dt = 0; dt < 4; ++dt)
        #pragma unroll
        for (int r = 0; r < 4; ++r) {
            int orow = w * 16 + (lane >> 4) * 4 + r;
            int oc = (dt * 16 + (lane & 15)) * 2;
            *(__bf16*)(Os + orow * 128 + (oc ^ ((orow & 7) << 4))) = (__bf16)(o[dt][r] * linv[r]);
        }
    __syncthreads();

    #pragma unroll
    for (int c = 0; c < 2; ++c) {
        int id = c * 256 + tid;
        int row = id >> 3, cc = id & 7;
        bf16x8 v = *(const bf16x8*)(Os + row * 128 + ((cc ^ (row & 7)) << 4));
        *(bf16x8*)(O + (size_t)(b * SEQ + qb * 64 + row) * DM + h * HD + cc * 8) = v;
    }
}

extern "C" void kernel_launch(void* const* d_in, const int* in_sizes, int n_in,
                              void* d_out, int out_size, void* d_ws, size_t ws_size,
                              hipStream_t stream) {
    const float* x  = (const float*)d_in[0];
    const float* wq = (const float*)d_in[1];
    const float* wk = (const float*)d_in[2];
    const float* wv = (const float*)d_in[3];
    const float* wo = (const float*)d_in[4];
    const int* tpos = (const int*)d_in[5];
    float* out = (float*)d_out;
    char* ws = (char*)d_ws;

    __bf16* xb   = (__bf16*)(ws);                        // 8 MB  [4096][1024]
    __bf16* wqkv = (__bf16*)(ws + (size_t)(8  << 20));   // 6 MB  [3072][1024]
    __bf16* wob  = (__bf16*)(ws + (size_t)(14 << 20));   // 2 MB  [1024][1024]
    __bf16* Qb   = (__bf16*)(ws + (size_t)(16 << 20));   // 8 MB  [32][2048][64]
    __bf16* Kb   = (__bf16*)(ws + (size_t)(24 << 20));   // 8 MB  [32][2048][64]
    __bf16* VTb  = (__bf16*)(ws + (size_t)(32 << 20));   // 8 MB  [32][64][2048]
    __bf16* Ob   = (__bf16*)(ws + (size_t)(40 << 20));   // 8 MB  [4096][1024]
    float* ct    = (float*)(ws + (size_t)(48 << 20));            // 256 KB
    float* st    = (float*)(ws + (size_t)(48 << 20) + 262144);   // 256 KB

    cvt_kernel<<<4096, 256, 0, stream>>>(x, xb, 4194304);
    cvt4_kernel<<<4096, 256, 0, stream>>>(wq, wk, wv, wo, wqkv, wob);
    rope_tab_kernel<<<256, 256, 0, stream>>>(ct, st);
    gemm_bt_kernel<0><<<dim3(24, 32), 256, 0, stream>>>(xb, wqkv, nullptr, Qb, Kb, VTb,
                                                        tpos, ct, st, 3072, 1024);
    attn_kernel<<<1024, 256, 0, stream>>>(Qb, Kb, VTb, Ob);
    gemm_bt_kernel<1><<<dim3(8, 32), 256, 0, stream>>>(Ob, wob, out, nullptr, nullptr, nullptr,
                                                       nullptr, nullptr, nullptr, 1024, 1024);
}

// Round 6
// 108.492 us; speedup vs baseline: 1.9085x; 1.0685x over previous
//
#include <hip/hip_runtime.h>
#include <stdint.h>
#include <stddef.h>

#define SEQ   2048
#define HD    64
#define DM    1024
#define NHEAD 16

typedef __bf16 bf16x8 __attribute__((ext_vector_type(8)));
typedef __bf16 bf16x4 __attribute__((ext_vector_type(4)));
typedef float  f32x4  __attribute__((ext_vector_type(4)));

#define MFMA16x16(a, b, c) __builtin_amdgcn_mfma_f32_16x16x32_bf16((a), (b), (c), 0, 0, 0)

__device__ __forceinline__ void gload16(const void* g, void* lds_uniform) {
    __builtin_amdgcn_global_load_lds(
        (const __attribute__((address_space(1))) uint32_t*)g,
        (__attribute__((address_space(3))) uint32_t*)lds_uniform, 16, 0, 0);
}

// ---------------- prep: fp32->bf16 for x + 4 weights, and rope tables, ONE launch ----
__global__ void prep_kernel(const float* __restrict__ x,
                            const float* __restrict__ wq, const float* __restrict__ wk,
                            const float* __restrict__ wv, const float* __restrict__ wo,
                            __bf16* __restrict__ xb, __bf16* __restrict__ wqkv,
                            __bf16* __restrict__ wob,
                            float* __restrict__ ct, float* __restrict__ st) {
    int bid = blockIdx.x;
    if (bid < 4096) {                       // x: 4M elements
        int i = (bid * 256 + threadIdx.x) * 4;
        const float4 v = *(const float4*)(x + i);
        __bf16 o[4] = {(__bf16)v.x, (__bf16)v.y, (__bf16)v.z, (__bf16)v.w};
        *(uint64_t*)(xb + i) = *(const uint64_t*)o;
    } else if (bid < 8192) {                // weights: 4 x 1M elements
        int g = (bid - 4096) >> 10;
        int i = (((bid - 4096) & 1023) * 256 + threadIdx.x) * 4;
        const float* src = (g == 0) ? wq : (g == 1) ? wk : (g == 2) ? wv : wo;
        __bf16* dst = (g == 3) ? wob : (wqkv + (size_t)g * 1048576);
        const float4 v = *(const float4*)(src + i);
        __bf16 o[4] = {(__bf16)v.x, (__bf16)v.y, (__bf16)v.z, (__bf16)v.w};
        *(uint64_t*)(dst + i) = *(const uint64_t*)o;
    } else {                                // rope tables: 65536 entries
        int i = (bid - 8192) * 256 + threadIdx.x;
        int p = i & 31;
        int pos = i >> 5;
        float freq = expf(-(float)p * (logf(10000.0f) / 32.0f));  // theta^(-p/32)
        float ang = (float)pos * freq;
        ct[i] = cosf(ang);
        st[i] = sinf(ang);
    }
}

// ---------------- GEMM: C[m][n] = sum_k A[m][k] * W[n][k]  (both K-contiguous) --------
// 128x128 tile, BK=64, 4 waves (2x2 of 64x64), global_load_lds(16B) staging with
// pre-swizzled source; LDS rows 128B, chunk XOR (row&7) swizzle -> conflict-free b128.
// Linear grid, XCD-chunked: xcd = bid&7 gets a contiguous bm-major chunk (bijective:
// grid size divisible by 8) -> per-kt L2 working set < 0.5MB per XCD.
// MODE 0: N=3072 QKV; epilogue scatters bf16 to Q[B,H,L,64], K[B,H,L,64], VT[B,H,64,L]
//         via a per-wave LDS transpose tile; RoPE fused for Q,K.
//         Q gets scale 0.125*log2(e) so attention softmax can use exp2.
// MODE 1: plain fp32 C output.
template <int MODE>
__global__ __launch_bounds__(256, 3)
void gemm_bt_kernel(const __bf16* __restrict__ A, const __bf16* __restrict__ W,
                    float* __restrict__ C, __bf16* __restrict__ Qb,
                    __bf16* __restrict__ Kb, __bf16* __restrict__ VTb,
                    const int* __restrict__ tpos, const float* __restrict__ ct,
                    const float* __restrict__ st, int N, int K) {
    __shared__ __align__(16) char smem[32768];
    char* As = smem;
    char* Bs = smem + 16384;
    const int lane = threadIdx.x & 63;
    const int w    = threadIdx.x >> 6;

    const int nbn = N >> 7;               // blocks along n
    const int per = (nbn * 32) >> 3;      // blocks per XCD (grid divisible by 8)
    const int id  = blockIdx.x;
    const int lin = (id & 7) * per + (id >> 3);
    const int bm  = lin / nbn;            // bm-major within the XCD chunk
    const int bn  = lin % nbn;

    const int rbase = (w >> 1) * 64;
    const int cbase = (w & 1) * 64;

    f32x4 acc[4][4] = {};

    const int kt_iters = K >> 6;
    for (int kt = 0; kt < kt_iters; ++kt) {
        #pragma unroll
        for (int c = 0; c < 4; ++c) {
            int id2 = (c * 4 + w) * 64 + lane;
            int row = id2 >> 3, cc = id2 & 7;
            int koff = kt * 64 + ((cc ^ (row & 7)) << 3);
            gload16(A + (size_t)(bm * 128 + row) * K + koff, As + (c * 4 + w) * 1024);
            gload16(W + (size_t)(bn * 128 + row) * K + koff, Bs + (c * 4 + w) * 1024);
        }
        __syncthreads();
        #pragma unroll
        for (int ks = 0; ks < 2; ++ks) {
            bf16x8 af[4], bfr[4];
            #pragma unroll
            for (int i = 0; i < 4; ++i) {
                int row = rbase + i * 16 + (lane & 15);
                int c = ks * 4 + (lane >> 4);
                af[i] = *(const bf16x8*)(As + row * 128 + ((c ^ (row & 7)) << 4));
            }
            #pragma unroll
            for (int j = 0; j < 4; ++j) {
                int row = cbase + j * 16 + (lane & 15);
                int c = ks * 4 + (lane >> 4);
                bfr[j] = *(const bf16x8*)(Bs + row * 128 + ((c ^ (row & 7)) << 4));
            }
            #pragma unroll
            for (int i = 0; i < 4; ++i)
                #pragma unroll
                for (int j = 0; j < 4; ++j)
                    acc[i][j] = MFMA16x16(af[i], bfr[j], acc[i][j]);
        }
        __syncthreads();
    }

    if (MODE == 1) {
        #pragma unroll
        for (int i = 0; i < 4; ++i)
            #pragma unroll
            for (int j = 0; j < 4; ++j)
                #pragma unroll
                for (int r = 0; r < 4; ++r) {
                    int m = bm * 128 + rbase + i * 16 + (lane >> 4) * 4 + r;
                    int n = bn * 128 + cbase + j * 16 + (lane & 15);
                    C[(size_t)m * N + n] = acc[i][j][r];
                }
    } else {
        const int which = bn >> 3;    // 0=Q 1=K 2=V (128-col block never crosses)
        char* T = smem + w * 8192;    // per-wave 64x64 bf16, swizzled
        #pragma unroll
        for (int i = 0; i < 4; ++i)
            #pragma unroll
            for (int j = 0; j < 4; ++j)
                #pragma unroll
                for (int r = 0; r < 4; ++r) {
                    int mi = i * 16 + (lane >> 4) * 4 + r;
                    int ni = j * 16 + (lane & 15);
                    __bf16 v = (__bf16)acc[i][j][r];
                    if (which == 2)
                        *(__bf16*)(T + ni * 128 + ((mi * 2) ^ ((ni & 7) << 4))) = v;
                    else
                        *(__bf16*)(T + mi * 128 + ((ni * 2) ^ ((mi & 7) << 4))) = v;
                }
        #pragma unroll
        for (int it = 0; it < 8; ++it) {
            int id2 = it * 64 + lane;
            int row = id2 >> 3, cc = id2 & 7;
            bf16x8 v = *(const bf16x8*)(T + row * 128 + ((cc ^ (row & 7)) << 4));
            if (which == 2) {
                int n = bn * 128 + cbase + row;       // d-major row
                int m = bm * 128 + rbase + cc * 8;    // 8 consecutive l
                int b = m >> 11, l = m & (SEQ - 1);
                int h = (n & (DM - 1)) >> 6, d = n & 63;
                *(bf16x8*)(VTb + ((size_t)((b * NHEAD + h) * HD + d) * SEQ) + l) = v;
            } else {
                int m = bm * 128 + rbase + row;
                int n = bn * 128 + cbase + cc * 8;    // 8 consecutive d
                int b = m >> 11, l = m & (SEQ - 1);
                int h = (n & (DM - 1)) >> 6, d = n & 63;
                // fused RoPE (pairs are even/odd within the 8 consecutive d)
                int pb = tpos[l] * 32 + (d >> 1);
                // Q: fold 1/sqrt(64) * log2(e) so softmax can use exp2
                float sc = (which == 0) ? 0.18033688011112042f : 1.0f;
                bf16x8 ov;
                #pragma unroll
                for (int jj = 0; jj < 4; ++jj) {
                    float cs = ct[pb + jj], sn = st[pb + jj];
                    float e = (float)v[2 * jj], dd = (float)v[2 * jj + 1];
                    ov[2 * jj]     = (__bf16)(sc * (cs * e - sn * dd));
                    ov[2 * jj + 1] = (__bf16)(sc * (sn * e + cs * dd));
                }
                __bf16* dst = which ? Kb : Qb;
                *(bf16x8*)(dst + ((size_t)(b * NHEAD + h) * SEQ + l) * HD + d) = ov;
            }
        }
    }
}

// ---------------- causal flash attention ----------------
// 1024 blocks (one 64-row q-tile each), XCD-pinned: xcd=bid&7 owns 4 heads
// (KV 2MB fits per-XCD L2). Within an XCD, qb DESCENDING so long blocks start
// first (greedy LPT packing). 4 blocks/CU by LDS (40960B), 16 waves/CU.
// K/V double-buffered: reg-staged prefetch issued before compute, swizzled
// ds_write after, ONE __syncthreads per iteration.
// Swapped QK^T: lane holds a full S-row slice -> softmax is a register tree.
// T13 defer-max: skip max-reduce + O-rescale unless __all(pmax<=mrow+8) fails.
// l-sum kept as per-lane partial, reduced once after the loop.
__global__ __launch_bounds__(256, 4)
void attn_kernel(const __bf16* __restrict__ Q, const __bf16* __restrict__ K,
                 const __bf16* __restrict__ VT, __bf16* __restrict__ O) {
    __shared__ __align__(16) char smem[40960];
    // buf0: K@0 V@8192 | buf1: K@16384 V@24576 | Ps/Os @32768 (8K)
    const int lane = threadIdx.x & 63;
    const int w    = threadIdx.x >> 6;
    const int tid  = threadIdx.x;
    char* Ps = smem + 32768 + w * 2048;   // per-wave [16 q][64 j] bf16 swz

    const int bid = blockIdx.x;
    const int xcd = bid & 7;
    const int idx = bid >> 3;             // 0..127 per XCD
    const int bh  = xcd * 4 + (idx & 3);  // 4 heads per XCD
    const int qb  = 31 - (idx >> 2);      // descending: longest first

    const __bf16* Qbh  = Q  + (size_t)bh * SEQ * HD;
    const __bf16* Kbh  = K  + (size_t)bh * SEQ * HD;
    const __bf16* VTbh = VT + (size_t)bh * HD * SEQ;
    const int b = bh >> 4, h = bh & 15;

    // prologue: stage tile 0 into buf0 (pre-swizzled source, linear LDS dest)
    #pragma unroll
    for (int c = 0; c < 2; ++c) {
        int id = (c * 4 + w) * 64 + lane;
        int row = id >> 3, cc = id & 7;
        int sw = (cc ^ (row & 7)) << 3;
        gload16(Kbh + (size_t)row * HD + sw, smem + (c * 4 + w) * 1024);
        gload16(VTbh + (size_t)row * SEQ + sw, smem + 8192 + (c * 4 + w) * 1024);
    }

    const int qrow = qb * 64 + w * 16 + (lane & 15);
    bf16x8 qf[2];
    qf[0] = *(const bf16x8*)(Qbh + (size_t)qrow * HD + (lane >> 4) * 8);
    qf[1] = *(const bf16x8*)(Qbh + (size_t)qrow * HD + 32 + (lane >> 4) * 8);

    f32x4 o[4] = {};
    float mrow = -1e30f;   // row max-so-far for row lane&15 (wave-uniform per row)
    float lrow = 0.f;      // PER-LANE partial sum (reduced after the loop)

    int cur = 0;
    __syncthreads();   // drains prologue gload_lds for all waves

    for (int kb = 0; kb <= qb; ++kb) {
        // issue next tile's loads to REGISTERS early (latency hides under compute)
        bf16x8 kreg[2], vreg[2];
        if (kb < qb) {
            #pragma unroll
            for (int c = 0; c < 2; ++c) {
                int id = c * 256 + tid;
                int row = id >> 3, cc = id & 7;
                kreg[c] = *(const bf16x8*)(Kbh + (size_t)((kb + 1) * 64 + row) * HD + cc * 8);
                vreg[c] = *(const bf16x8*)(VTbh + (size_t)row * SEQ + (kb + 1) * 64 + cc * 8);
            }
        }

        char* Ks = smem + cur * 16384;
        char* Vs = Ks + 8192;

        // swapped QK^T: lane holds row i = lane&15 (wave-local),
        // j = kb*64 + jt*16 + (lane>>4)*4 + r
        f32x4 s[4];
        #pragma unroll
        for (int jt = 0; jt < 4; ++jt) {
            f32x4 z = {};
            #pragma unroll
            for (int ks = 0; ks < 2; ++ks) {
                int row = jt * 16 + (lane & 15);
                int c = ks * 4 + (lane >> 4);
                bf16x8 kf = *(const bf16x8*)(Ks + row * 128 + ((c ^ (row & 7)) << 4));
                z = MFMA16x16(kf, qf[ks], z);
            }
            s[jt] = z;
        }

        if (kb == qb) {
            int i = qb * 64 + w * 16 + (lane & 15);
            #pragma unroll
            for (int jt = 0; jt < 4; ++jt)
                #pragma unroll
                for (int r = 0; r < 4; ++r) {
                    int j = kb * 64 + jt * 16 + (lane >> 4) * 4 + r;
                    if (j > i) s[jt][r] = -1e30f;
                }
        }

        // per-lane partial max over this lane's 16 values
        float pmax = fmaxf(fmaxf(fmaxf(s[0][0], s[0][1]), fmaxf(s[0][2], s[0][3])),
                           fmaxf(fmaxf(s[1][0], s[1][1]), fmaxf(s[1][2], s[1][3])));
        pmax = fmaxf(pmax,
               fmaxf(fmaxf(fmaxf(s[2][0], s[2][1]), fmaxf(s[2][2], s[2][3])),
                     fmaxf(fmaxf(s[3][0], s[3][1]), fmaxf(s[3][2], s[3][3]))));

        // T13 defer-max: only do the full reduce + rescale when needed (rare)
        if (!__all(pmax <= mrow + 8.0f)) {
            pmax = fmaxf(pmax, __shfl_xor(pmax, 16));
            pmax = fmaxf(pmax, __shfl_xor(pmax, 32));
            float mn = fmaxf(mrow, pmax);
            float alpha = exp2f(mrow - mn);
            mrow = mn;
            lrow *= alpha;                       // per-lane partial, alpha row-uniform
            float ar[4];
            #pragma unroll
            for (int r = 0; r < 4; ++r) ar[r] = __shfl(alpha, (lane >> 4) * 4 + r);
            #pragma unroll
            for (int dt = 0; dt < 4; ++dt)
                #pragma unroll
                for (int r = 0; r < 4; ++r)
                    o[dt][r] *= ar[r];
        }

        // exp2, accumulate per-lane partial sum, pack 4 bf16 -> one ds_write_b64
        {
            int qr = lane & 15;
            int swrow = (qr & 7) << 4;
            float rs = 0.f;
            #pragma unroll
            for (int jt = 0; jt < 4; ++jt) {
                bf16x4 pk;
                #pragma unroll
                for (int r = 0; r < 4; ++r) {
                    float pv = exp2f(s[jt][r] - mrow);
                    rs += pv;
                    pk[r] = (__bf16)pv;
                }
                int jj = (jt * 16 + (lane >> 4) * 4) * 2;
                *(bf16x4*)(Ps + qr * 128 + (jj ^ swrow)) = pk;
            }
            lrow += rs;
        }

        // PV: O[q][d] += P[q][j] * VT[d][j]
        #pragma unroll
        for (int js = 0; js < 2; ++js) {
            int prow = lane & 15;
            int cb = js * 4 + (lane >> 4);
            bf16x8 pf = *(const bf16x8*)(Ps + prow * 128 + ((cb ^ (prow & 7)) << 4));
            #pragma unroll
            for (int dt = 0; dt < 4; ++dt) {
                int vrow = dt * 16 + (lane & 15);
                bf16x8 vf = *(const bf16x8*)(Vs + vrow * 128 + ((cb ^ (vrow & 7)) << 4));
                o[dt] = MFMA16x16(pf, vf, o[dt]);
            }
        }

        // write prefetched tile into the OTHER buffer (vmcnt waits auto-inserted)
        if (kb < qb) {
            char* Kn = smem + (cur ^ 1) * 16384;
            char* Vn = Kn + 8192;
            #pragma unroll
            for (int c = 0; c < 2; ++c) {
                int id = c * 256 + tid;
                int row = id >> 3, cc = id & 7;
                int sw = (cc ^ (row & 7)) << 4;
                *(bf16x8*)(Kn + row * 128 + sw) = kreg[c];
                *(bf16x8*)(Vn + row * 128 + sw) = vreg[c];
            }
        }
        __syncthreads();
        cur ^= 1;
    }

    // reduce per-lane partial l over the 4 lanes of each row, then broadcast
    lrow += __shfl_xor(lrow, 16);
    lrow += __shfl_xor(lrow, 32);
    float linv[4];
    #pragma unroll
    for (int r = 0; r < 4; ++r) {
        float lr = __shfl(lrow, (lane >> 4) * 4 + r);
        linv[r] = 1.0f / lr;
    }

    // stage O tile [64 q][64 d] into the P region (each wave its own 2KB), then store
    char* Os = smem + 32768;
    #pragma unroll
    for (int dt = 0; dt < 4; ++dt)
        #pragma unroll
        for (int r = 0; r < 4; ++r) {
            int orow = w * 16 + (lane >> 4) * 4 + r;
            int oc = (dt * 16 + (lane & 15)) * 2;
            *(__bf16*)(Os + orow * 128 + (oc ^ ((orow & 7) << 4))) = (__bf16)(o[dt][r] * linv[r]);
        }
    __syncthreads();

    #pragma unroll
    for (int c = 0; c < 2; ++c) {
        int id = c * 256 + tid;
        int row = id >> 3, cc = id & 7;
        bf16x8 v = *(const bf16x8*)(Os + row * 128 + ((cc ^ (row & 7)) << 4));
        *(bf16x8*)(O + (size_t)(b * SEQ + qb * 64 + row) * DM + h * HD + cc * 8) = v;
    }
}

extern "C" void kernel_launch(void* const* d_in, const int* in_sizes, int n_in,
                              void* d_out, int out_size, void* d_ws, size_t ws_size,
                              hipStream_t stream) {
    const float* x  = (const float*)d_in[0];
    const float* wq = (const float*)d_in[1];
    const float* wk = (const float*)d_in[2];
    const float* wv = (const float*)d_in[3];
    const float* wo = (const float*)d_in[4];
    const int* tpos = (const int*)d_in[5];
    float* out = (float*)d_out;
    char* ws = (char*)d_ws;

    __bf16* xb   = (__bf16*)(ws);                        // 8 MB  [4096][1024]
    __bf16* wqkv = (__bf16*)(ws + (size_t)(8  << 20));   // 6 MB  [3072][1024]
    __bf16* wob  = (__bf16*)(ws + (size_t)(14 << 20));   // 2 MB  [1024][1024]
    __bf16* Qb   = (__bf16*)(ws + (size_t)(16 << 20));   // 8 MB  [32][2048][64]
    __bf16* Kb   = (__bf16*)(ws + (size_t)(24 << 20));   // 8 MB  [32][2048][64]
    __bf16* VTb  = (__bf16*)(ws + (size_t)(32 << 20));   // 8 MB  [32][64][2048]
    __bf16* Ob   = (__bf16*)(ws + (size_t)(40 << 20));   // 8 MB  [4096][1024]
    float* ct    = (float*)(ws + (size_t)(48 << 20));            // 256 KB
    float* st    = (float*)(ws + (size_t)(48 << 20) + 262144);   // 256 KB

    prep_kernel<<<8448, 256, 0, stream>>>(x, wq, wk, wv, wo, xb, wqkv, wob, ct, st);
    gemm_bt_kernel<0><<<768, 256, 0, stream>>>(xb, wqkv, nullptr, Qb, Kb, VTb,
                                               tpos, ct, st, 3072, 1024);
    attn_kernel<<<1024, 256, 0, stream>>>(Qb, Kb, VTb, Ob);
    gemm_bt_kernel<1><<<256, 256, 0, stream>>>(Ob, wob, out, nullptr, nullptr, nullptr,
                                               nullptr, nullptr, nullptr, 1024, 1024);
}